// Round 16
// baseline (334.817 us; speedup 1.0000x reference)
//
#include <hip/hip_runtime.h>
#include <stdint.h>

using bf16x8 = __attribute__((ext_vector_type(8))) short;
using bf16x8_t = __attribute__((ext_vector_type(8))) __bf16;
using f32x4  = __attribute__((ext_vector_type(4))) float;
typedef unsigned short u16;
typedef unsigned int   u32;

#define DEVI static __device__ __forceinline__

typedef u32 __attribute__((address_space(1))) gu32;
typedef u32 __attribute__((address_space(3))) lu32;

DEVI u16 f2b(float f) {
  union { float f; u32 u; } v; v.f = f;
  u32 r = v.u + 0x7FFFu + ((v.u >> 16) & 1u);
  return (u16)(r >> 16);
}

DEVI f32x4 mfma16(bf16x8 a, bf16x8 b, f32x4 c) {
  return __builtin_amdgcn_mfma_f32_16x16x32_bf16(
      __builtin_bit_cast(bf16x8_t, a), __builtin_bit_cast(bf16x8_t, b), c, 0, 0, 0);
}

DEVI void gload16(const void* g, void* l) {
  __builtin_amdgcn_global_load_lds((const gu32*)(uintptr_t)g,
                                   (lu32*)(u32)(uintptr_t)l, 16, 0, 0);
}

// XOR-swizzled u16 index of 16B chunk `ch` (0..7) in row `row` of a [*][64] u16
// tile (phys chunk = logical chunk ^ (row&7)). DMA staging keeps LDS linear and
// pre-swizzles the GLOBAL source chunk instead (guide rule #21).
DEVI int swz64(int row, int ch) { return row*64 + ((ch ^ (row & 7)) << 3); }

// Swizzled addressing for the inversion branch's [64][128] f32 matrix (exactly
// 32768B, no pad). Physical float4 slot = logical ^ (row&31): per-lane own-row
// accesses conflict-free, same-slot broadcasts free.
DEVI int a4x(int row, int s4) { return row*32 + (s4 ^ (row & 31)); }           // float4 units
DEVI int awx(int row, int wd) { return row*128 + (((wd >> 2) ^ (row & 31)) << 2) + (wd & 3); } // f32 units

#define VMCNT0 asm volatile("s_waitcnt vmcnt(0)" ::: "memory")
#define LGKM0  asm volatile("s_waitcnt lgkmcnt(0)" ::: "memory")

// ---------------- casts ----------------
__global__ void __launch_bounds__(256) k_cast_x(const float4* __restrict__ xin,
                                                uint4* __restrict__ xo, int n8) {
  int i = blockIdx.x * 256 + threadIdx.x;
  if (i >= n8) return;
  float4 a = xin[2*i], b = xin[2*i+1];
  uint4 o;
  o.x = ((u32)f2b(a.y) << 16) | f2b(a.x);
  o.y = ((u32)f2b(a.w) << 16) | f2b(a.z);
  o.z = ((u32)f2b(b.y) << 16) | f2b(b.x);
  o.w = ((u32)f2b(b.w) << 16) | f2b(b.z);
  xo[i] = o;
}

// w [R][Cc] f32 -> wt [Cc][R] bf16
__global__ void __launch_bounds__(256) k_tcast(const float* __restrict__ w,
                                               u16* __restrict__ wt, int R, int Cc) {
  int o = blockIdx.x * 256 + threadIdx.x;
  if (o >= R * Cc) return;
  int c = o % R, j = o / R;
  wt[o] = f2b(w[(size_t)c * Cc + j]);
}

// ---------------- exact f32 landmark q_l / k_l ----------------
__global__ void __launch_bounds__(256) k_lmk(
    const float* __restrict__ x, const float* __restrict__ w,
    const float* __restrict__ bias, float* __restrict__ qlf,
    float* __restrict__ klf, u16* __restrict__ qlb, u16* __restrict__ klb) {
  __shared__ __align__(16) float xr[512];
  const int t = threadIdx.x;
  const int b = blockIdx.x >> 6, i = blockIdx.x & 63;
  const int idx = (i * 8191) / 63;   // == np.linspace(0,8191,64).astype(int32)
  const float4* xg = (const float4*)(x + ((size_t)b*8192 + idx)*512);
  if (t < 128) ((float4*)xr)[t] = xg[t];
  __syncthreads();

  const int o0 = t << 2;
  float4 acc = *(const float4*)(bias + o0);
  const float* wp = w + o0;
  #pragma unroll 8
  for (int c = 0; c < 512; ++c) {
    const float xv = xr[c];
    const float4 wv = *(const float4*)(wp + (size_t)c*1536);
    acc.x = fmaf(xv, wv.x, acc.x); acc.y = fmaf(xv, wv.y, acc.y);
    acc.z = fmaf(xv, wv.z, acc.z); acc.w = fmaf(xv, wv.w, acc.w);
  }

  const int h = (o0 >> 6) & 7, d = o0 & 63;
  const size_t ofs = ((size_t)(b*8 + h)*64 + i)*64 + d;
  ushort4 pk;
  pk.x = f2b(acc.x); pk.y = f2b(acc.y); pk.z = f2b(acc.z); pk.w = f2b(acc.w);
  if (o0 < 512) { *(float4*)(qlf + ofs) = acc; *(ushort4*)(qlb + ofs) = pk; }
  else          { *(float4*)(klf + ofs) = acc; *(ushort4*)(klb + ofs) = pk; }
}

// ---------------- fused K2 softmax + SINGLE-WAVE Gauss-Jordan inverse ----------------
// r16: rounds 10-15 proved the fused makespan is inv-CHAIN-bound (~150us): the
// 64-col x 2-__syncthreads GJ stalls on barrier rescheduling when CUs are crowded
// with gemm waves (VGPR 116/124/132 all gave ~150; MfmaUtil halved = gemm tail
// idle). This version: ONE wave owns the whole matrix (lane l <-> row l), zero
// barriers; cross-lane LDS dataflow ordered by per-column lgkmcnt(0) + memory
// clobber (rule #18). Broadcast pivot-row reads are conflict-free; own-row
// accesses conflict-free via a4x swizzle. Update skips provably-zero slots.
__device__ __noinline__ void inv_body(
    char* smem, const float* __restrict__ qlf, const float* __restrict__ klf,
    float* __restrict__ invg, int bh, int l) {
  float* Am = (float*)smem;
  float4* A4 = (float4*)smem;

  // stage k_l into right half (coalesced global reads, swizzled LDS writes)
  const float4* kg = (const float4*)(klf + (size_t)bh*4096);
  #pragma unroll 1
  for (int g = l; g < 1024; g += 64)
    A4[a4x(g >> 4, 16 + (g & 15))] = kg[g];
  LGKM0; asm volatile("" ::: "memory");

  // logits row l -> left half: Am[l][j] = (q_l[l].k_l[j]) * 0.125
  // q chunked from L2 (16 floats at a time); k rows are wave-broadcast LDS reads
  const float4* qg = (const float4*)(qlf + (size_t)bh*4096) + (size_t)l*16;
  #pragma unroll 1
  for (int jb = 0; jb < 4; ++jb) {
    float acc[16];
    #pragma unroll
    for (int jj = 0; jj < 16; ++jj) acc[jj] = 0.f;
    #pragma unroll 1
    for (int ch = 0; ch < 4; ++ch) {
      float4 qc[4];
      #pragma unroll
      for (int i = 0; i < 4; ++i) qc[i] = qg[ch*4 + i];
      #pragma unroll
      for (int jj = 0; jj < 16; ++jj) {
        const int j = jb*16 + jj;
        float a = acc[jj];
        #pragma unroll
        for (int i = 0; i < 4; ++i) {
          float4 kv = A4[a4x(j, 16 + ch*4 + i)];
          a = fmaf(qc[i].x, kv.x, a); a = fmaf(qc[i].y, kv.y, a);
          a = fmaf(qc[i].z, kv.z, a); a = fmaf(qc[i].w, kv.w, a);
        }
        acc[jj] = a;
      }
    }
    #pragma unroll
    for (int jj = 0; jj < 16; ++jj)
      Am[awx(l, jb*16 + jj)] = acc[jj] * 0.125f;
  }

  // softmax of own row (lane-local float4 passes) + identity augment
  float mr = -1e30f;
  #pragma unroll 1
  for (int i = 0; i < 16; ++i) {
    float4 v = A4[a4x(l, i)];
    mr = fmaxf(mr, fmaxf(fmaxf(v.x, v.y), fmaxf(v.z, v.w)));
  }
  float sr = 0.f;
  #pragma unroll 1
  for (int i = 0; i < 16; ++i) {
    float4 v = A4[a4x(l, i)];
    v.x = __expf(v.x - mr); v.y = __expf(v.y - mr);
    v.z = __expf(v.z - mr); v.w = __expf(v.w - mr);
    sr += v.x + v.y + v.z + v.w;
    A4[a4x(l, i)] = v;
  }
  const float rinv = 1.f / sr;
  #pragma unroll 1
  for (int i = 0; i < 16; ++i) {
    float4 v = A4[a4x(l, i)];
    v.x *= rinv; v.y *= rinv; v.z *= rinv; v.w *= rinv;
    A4[a4x(l, i)] = v;
    float4 e = {0.f, 0.f, 0.f, 0.f};
    const int base = i*4;
    if (base     == l) e.x = 1.f;
    if (base + 1 == l) e.y = 1.f;
    if (base + 2 == l) e.z = 1.f;
    if (base + 3 == l) e.w = 1.f;
    A4[a4x(l, 16 + i)] = e;
  }
  LGKM0; asm volatile("" ::: "memory");

  // Gauss-Jordan, barrier-free: virtual pivot, no normalize
  int used = 0, mypivc = 0;
  #pragma unroll 1
  for (int c = 0; c < 64; ++c) {
    const float ac = Am[awx(l, c)];
    float val = used ? -1.f : fabsf(ac);
    int idx = l;
    #pragma unroll
    for (int mk = 1; mk < 64; mk <<= 1) {
      float ov = __shfl_xor(val, mk);
      int oi = __shfl_xor(idx, mk);
      int take = (ov > val) || (ov == val && oi < idx);
      val = take ? ov : val;
      idx = take ? oi : idx;
    }
    const int p = idx;                       // uniform across lanes
    if (l == p) { used = 1; mypivc = c; }
    const float coef = -ac / Am[awx(p, c)];  // broadcast LDS read
    if (l != p) {
      #pragma unroll 1
      for (int s4 = c >> 2; s4 < 32; ++s4) { // slots < c>>2: pivot row is 0 there
        float4 a = A4[a4x(l, s4)];
        float4 pv = A4[a4x(p, s4)];          // broadcast
        a.x = fmaf(coef, pv.x, a.x); a.y = fmaf(coef, pv.y, a.y);
        a.z = fmaf(coef, pv.z, a.z); a.w = fmaf(coef, pv.w, a.w);
        A4[a4x(l, s4)] = a;
      }
    }
    LGKM0; asm volatile("" ::: "memory");    // updates visible before next scan
  }

  // extraction: lane l holds row mypivc of the inverse; divide by final diag
  const float rd = 1.f / Am[awx(l, mypivc)];
  float4* og = (float4*)(invg + (size_t)bh*4096 + (size_t)mypivc*64);
  #pragma unroll 1
  for (int i = 0; i < 16; ++i) {
    float4 v = A4[a4x(l, 16 + i)];
    v.x *= rd; v.y *= rd; v.z *= rd; v.w *= rd;
    og[i] = v;
  }
}

// ---------------- 128x128 tile bf16 MFMA GEMM (A[M][K] @ Bt[N][K]^T) ----------------
// MODE 0: qkv epilogue + 32 fused K2-inversion blocks (wgid<32: wave0 runs the
// barrier-free single-wave inverse, waves 1-3 exit).
// MODE 1: f32 epilogue (out[M][Nout] = acc + bias), no fusion.
template <int MODE>
__global__ void __launch_bounds__(256) k_gemm(
    const u16* __restrict__ A, const u16* __restrict__ Bt,
    const float* __restrict__ bias, int K, int ntn,
    u16* __restrict__ qdst, u16* __restrict__ kdst, u16* __restrict__ vtdst,
    float* __restrict__ fout, int Nout,
    const float* __restrict__ qlf, const float* __restrict__ klf,
    float* __restrict__ invg) {
  __shared__ __align__(16) char smem[32768];
  const int t = threadIdx.x;
  // XCD swizzle: gridDim.x % 8 == 0 for all call sites -> bijective
  const int cpx = gridDim.x >> 3;
  const int wgid = (blockIdx.x & 7) * cpx + (blockIdx.x >> 3);

  if (MODE == 0 && wgid < 32) {
    if (t < 64) inv_body(smem, qlf, klf, invg, wgid, t);
    return;
  }

  // ======== GEMM path ========
  u16* As = (u16*)smem;
  u16* Bs = (u16*)(smem + 16384);
  const int wg2 = wgid - (MODE == 0 ? 32 : 0);
  const int tn = wg2 % ntn, tm = wg2 / ntn;
  const int m0 = tm << 7, n0 = tn << 7;
  const int w = t >> 6, l = t & 63;
  const int wr = (w >> 1) << 6, wc = (w & 1) << 6;
  const int lhi = l >> 4, llo = l & 15;

  f32x4 acc[4][4];
  #pragma unroll
  for (int i = 0; i < 4; ++i)
    #pragma unroll
    for (int j = 0; j < 4; ++j) acc[i][j] = f32x4{0.f,0.f,0.f,0.f};

  // staged rows advance by 32 (≡0 mod 8), so row&7 == (t>>3)&7 for all i
  const int csw = (((t & 7) ^ ((t >> 3) & 7)) << 3);
  const u16* ga = A  + (size_t)(m0 + (t >> 3)) * K + csw;
  const u16* gb = Bt + (size_t)(n0 + (t >> 3)) * K + csw;
  u16* lA = As + (w << 9);
  u16* lB = Bs + (w << 9);

  for (int kt = 0; kt < K; kt += 64) {
    __syncthreads();
    #pragma unroll
    for (int i = 0; i < 4; ++i) {
      gload16(ga + (size_t)(i*32)*K + kt, lA + i*2048);
      gload16(gb + (size_t)(i*32)*K + kt, lB + i*2048);
    }
    VMCNT0;
    __syncthreads();
    #pragma unroll
    for (int kko = 0; kko < 64; kko += 32) {
      const int kc = kko >> 3;     // chunk base: 0 or 4
      bf16x8 av[4], bv[4];
      #pragma unroll
      for (int mi = 0; mi < 4; ++mi)
        av[mi] = *(const bf16x8*)(As + swz64(wr + mi*16 + llo, kc + lhi));
      #pragma unroll
      for (int ni = 0; ni < 4; ++ni)
        bv[ni] = *(const bf16x8*)(Bs + swz64(wc + ni*16 + llo, kc + lhi));
      #pragma unroll
      for (int mi = 0; mi < 4; ++mi)
        #pragma unroll
        for (int ni = 0; ni < 4; ++ni)
          acc[mi][ni] = mfma16(av[mi], bv[ni], acc[mi][ni]);
    }
  }

  #pragma unroll
  for (int ni = 0; ni < 4; ++ni) {
    const int gcol = n0 + wc + ni*16 + llo;
    const float bvv = bias[gcol];
    if (MODE == 0) {
      const int tt = gcol >> 9, h = (gcol >> 6) & 7, d = gcol & 63;
      #pragma unroll
      for (int mi = 0; mi < 4; ++mi) {
        const int grow = m0 + wr + mi*16 + (lhi << 2);
        const int b = grow >> 13, n = grow & 8191;
        const size_t bh = (size_t)(b*8 + h);
        if (tt == 2) {
          ushort4 pk;
          pk.x = f2b(acc[mi][ni][0] + bvv); pk.y = f2b(acc[mi][ni][1] + bvv);
          pk.z = f2b(acc[mi][ni][2] + bvv); pk.w = f2b(acc[mi][ni][3] + bvv);
          *(ushort4*)(vtdst + (bh*64 + d)*8192 + n) = pk;
        } else {
          u16* dst = (tt == 0 ? qdst : kdst) + (bh*8192 + n)*64 + d;
          #pragma unroll
          for (int r = 0; r < 4; ++r) dst[(size_t)r*64] = f2b(acc[mi][ni][r] + bvv);
        }
      }
    } else {
      #pragma unroll
      for (int mi = 0; mi < 4; ++mi) {
        const int grow = m0 + wr + mi*16 + (lhi << 2);
        #pragma unroll
        for (int r = 0; r < 4; ++r)
          fout[(size_t)(grow + r)*Nout + gcol] = acc[mi][ni][r] + bvv;
      }
    }
  }
}

// ---------------- kernel_3 partials: num = sum_n e^{q_l.k/8} v, den = sum_n e^{...} ----------------
__global__ void __launch_bounds__(256) k_flash3(
    const u16* __restrict__ qlb, const u16* __restrict__ kmat,
    const u16* __restrict__ vt, float* __restrict__ num_part,
    float* __restrict__ den_part) {
  __shared__ __align__(16) u16 QL[64*64];
  __shared__ __align__(16) u16 KT[4][64*64];
  __shared__ __align__(16) u16 VT[4][64*64];
  __shared__ __align__(16) u16 PL[4][64*64];
  const int t = threadIdx.x, w = t >> 6, l = t & 63;
  const int bh = blockIdx.x >> 3, split = blockIdx.x & 7;
  const int lhi = l >> 4, llo = l & 15;
  const int csw = ((l & 7) ^ (l >> 3)) << 3;       // source chunk pre-swizzle

  #pragma unroll
  for (int i = 0; i < 2; ++i)
    gload16(qlb + (size_t)bh*4096 + (size_t)((i*256 + (t & ~7)) << 3)
                + (((t & 7) ^ ((t >> 3) & 7)) << 3),
            QL + i*2048 + (w << 9));
  VMCNT0;
  __syncthreads();

  f32x4 oacc[4][4];
  float dacc[4][4];
  #pragma unroll
  for (int a = 0; a < 4; ++a)
    #pragma unroll
    for (int bq = 0; bq < 4; ++bq) { oacc[a][bq] = f32x4{0.f,0.f,0.f,0.f}; dacc[a][bq] = 0.f; }

  const int nb = split << 10;
  u16* lk = KT[w]; u16* lv = VT[w]; u16* lp = PL[w];
  for (int j = 0; j < 4; ++j) {
    const int n0 = nb + ((w + 4*j) << 6);
    const u16* gk = kmat + ((size_t)bh*8192 + n0 + (l >> 3))*64 + csw;
    const u16* gv = vt   + ((size_t)bh*64 + (l >> 3))*8192 + n0 + csw;
    asm volatile("" ::: "memory");
    LGKM0;   // drain prior iter's ds_reads before DMA overwrites lk/lv
    #pragma unroll
    for (int i = 0; i < 8; ++i) {
      gload16(gk + (size_t)(i*8)*64, lk + i*512);
      gload16(gv + (size_t)(i*8)*8192, lv + i*512);
    }
    VMCNT0;

    f32x4 s[4][4];
    #pragma unroll
    for (int qi = 0; qi < 4; ++qi)
      #pragma unroll
      for (int nj = 0; nj < 4; ++nj) s[qi][nj] = f32x4{0.f,0.f,0.f,0.f};
    #pragma unroll
    for (int kko = 0; kko < 64; kko += 32) {
      const int kc = kko >> 3;
      bf16x8 av[4], bv[4];
      #pragma unroll
      for (int qi = 0; qi < 4; ++qi)
        av[qi] = *(const bf16x8*)(QL + swz64(qi*16 + llo, kc + lhi));
      #pragma unroll
      for (int nj = 0; nj < 4; ++nj)
        bv[nj] = *(const bf16x8*)(lk + swz64(nj*16 + llo, kc + lhi));
      #pragma unroll
      for (int qi = 0; qi < 4; ++qi)
        #pragma unroll
        for (int nj = 0; nj < 4; ++nj)
          s[qi][nj] = mfma16(av[qi], bv[nj], s[qi][nj]);
    }
    #pragma unroll
    for (int qi = 0; qi < 4; ++qi) {
      float rs[4] = {0.f, 0.f, 0.f, 0.f};
      #pragma unroll
      for (int nj = 0; nj < 4; ++nj)
        #pragma unroll
        for (int r = 0; r < 4; ++r) {
          float p = __expf(s[qi][nj][r] * 0.125f);  // logits bounded, no max needed
          rs[r] += p;
          const int prow = qi*16 + lhi*4 + r, pcol = nj*16 + llo;
          lp[swz64(prow, pcol >> 3) + (pcol & 7)] = f2b(p);
        }
      #pragma unroll
      for (int r = 0; r < 4; ++r) {
        float v = rs[r];
        v += __shfl_xor(v, 1); v += __shfl_xor(v, 2);
        v += __shfl_xor(v, 4); v += __shfl_xor(v, 8);
        dacc[qi][r] += v;
      }
    }
    LGKM0;
    #pragma unroll
    for (int kko = 0; kko < 64; kko += 32) {
      const int kc = kko >> 3;
      bf16x8 pa[4], vb[4];
      #pragma unroll
      for (int qi = 0; qi < 4; ++qi)
        pa[qi] = *(const bf16x8*)(lp + swz64(qi*16 + llo, kc + lhi));
      #pragma unroll
      for (int dj = 0; dj < 4; ++dj)
        vb[dj] = *(const bf16x8*)(lv + swz64(dj*16 + llo, kc + lhi));
      #pragma unroll
      for (int qi = 0; qi < 4; ++qi)
        #pragma unroll
        for (int dj = 0; dj < 4; ++dj)
          oacc[qi][dj] = mfma16(pa[qi], vb[dj], oacc[qi][dj]);
    }
  }
  const int sw = (split << 2) + w;
  float* np = num_part + ((size_t)bh*32 + sw)*4096;
  #pragma unroll
  for (int qi = 0; qi < 4; ++qi)
    #pragma unroll
    for (int dj = 0; dj < 4; ++dj)
      #pragma unroll
      for (int r = 0; r < 4; ++r)
        np[(qi*16 + lhi*4 + r)*64 + dj*16 + llo] = oacc[qi][dj][r];
  if (llo == 0) {
    float* dp = den_part + ((size_t)bh*32 + sw)*64;
    #pragma unroll
    for (int qi = 0; qi < 4; ++qi)
      #pragma unroll
      for (int r = 0; r < 4; ++r)
        dp[qi*16 + lhi*4 + r] = dacc[qi][r];
  }
}

// ---------------- T1 = (sum_s num_part) / den : wide reduce ----------------
__global__ void __launch_bounds__(256) k_t1(
    const float* __restrict__ num_part, const float* __restrict__ den_part,
    float* __restrict__ t1g) {
  const int t = threadIdx.x;
  const int bh = blockIdx.x >> 2, ch = blockIdx.x & 3;
  const int f = ch*256 + t;                 // float4 index in [0,1024)
  const int m = f >> 4;                     // landmark row
  const float4* ng = (const float4*)num_part + (size_t)bh*32*1024;
  float4 acc = {0.f, 0.f, 0.f, 0.f};
  float ds = 0.f;
  for (int s = 0; s < 32; ++s) {
    float4 v = ng[(size_t)s*1024 + f];
    acc.x += v.x; acc.y += v.y; acc.z += v.z; acc.w += v.w;
    ds += den_part[((size_t)bh*32 + s)*64 + m];
  }
  float r = 1.f / ds;
  acc.x *= r; acc.y *= r; acc.z *= r; acc.w *= r;
  ((float4*)t1g)[(size_t)bh*1024 + f] = acc;
}

// ---------------- t2^T = (Inv @ T1)^T ----------------
__global__ void __launch_bounds__(256) k_t2(
    const float* __restrict__ invg, const float* __restrict__ t1g,
    float* __restrict__ t2t) {
  __shared__ __align__(16) float IV[64*68];
  __shared__ __align__(16) float T1[64*68];
  const int t = threadIdx.x;
  const int bh = blockIdx.x;
  const int i4 = t >> 2, jc = t & 3;
  float4* IV4 = (float4*)IV;
  float4* T14 = (float4*)T1;
  const float4* ig = (const float4*)(invg + (size_t)bh*4096);
  const float4* tg = (const float4*)(t1g + (size_t)bh*4096);
  #pragma unroll
  for (int k = 0; k < 4; ++k) {
    int g = k*256 + t, row = g >> 4, c4 = g & 15;
    IV4[row*17 + c4] = ig[g];
    T14[row*17 + c4] = tg[g];
  }
  __syncthreads();
  float acc[16];
  #pragma unroll
  for (int d = 0; d < 16; ++d) acc[d] = 0.f;
  for (int m = 0; m < 64; ++m) {
    float wv = IV[i4*68 + m];
    #pragma unroll
    for (int d4 = 0; d4 < 4; ++d4) {
      float4 tv = T14[m*17 + jc*4 + d4];
      acc[d4*4+0] = fmaf(wv, tv.x, acc[d4*4+0]);
      acc[d4*4+1] = fmaf(wv, tv.y, acc[d4*4+1]);
      acc[d4*4+2] = fmaf(wv, tv.z, acc[d4*4+2]);
      acc[d4*4+3] = fmaf(wv, tv.w, acc[d4*4+3]);
    }
  }
  #pragma unroll
  for (int dd = 0; dd < 16; ++dd) {
    int d = jc*16 + dd;
    t2t[((size_t)bh*64 + d)*64 + i4] = acc[dd];
  }
}

// ---------------- fused kernel_1 softmax + @t2 -> out_att bf16 [B][N][C] ----------------
__global__ void __launch_bounds__(256) k_flash1(
    const u16* __restrict__ q, const u16* __restrict__ klb,
    const float* __restrict__ t2t, u16* __restrict__ oatt) {
  __shared__ __align__(16) u16 KL[64*64];
  __shared__ __align__(16) u16 T2[64*64];
  __shared__ __align__(16) u16 QT[4][64*64];
  __shared__ __align__(16) u16 PL[4][64*64];
  const int t = threadIdx.x, w = t >> 6, l = t & 63;
  const int bh = blockIdx.x >> 5, blk = blockIdx.x & 31;
  const int lhi = l >> 4, llo = l & 15;
  const int b = bh >> 3, h = bh & 7;
  const int csw = ((l & 7) ^ (l >> 3)) << 3;

  #pragma unroll
  for (int i = 0; i < 2; ++i)
    gload16(klb + (size_t)bh*4096 + (size_t)((i*256 + (t & ~7)) << 3)
                + (((t & 7) ^ ((t >> 3) & 7)) << 3),
            KL + i*2048 + (w << 9));
  for (int i = t; i < 4096; i += 256)
    T2[swz64(i >> 6, (i & 63) >> 3) + (i & 7)] = f2b(t2t[(size_t)bh*4096 + i]);
  VMCNT0;
  __syncthreads();

  const int n0 = (blk << 8) + (w << 6);
  const u16* gq = q + ((size_t)bh*8192 + n0 + (l >> 3))*64 + csw;
  u16* lq = QT[w]; u16* lp = PL[w];
  #pragma unroll
  for (int i = 0; i < 8; ++i) gload16(gq + (size_t)(i*8)*64, lq + i*512);
  VMCNT0;

  f32x4 s[4][4];
  #pragma unroll
  for (int qi = 0; qi < 4; ++qi)
    #pragma unroll
    for (int nj = 0; nj < 4; ++nj) s[qi][nj] = f32x4{0.f,0.f,0.f,0.f};
  #pragma unroll
  for (int kko = 0; kko < 64; kko += 32) {
    const int kc = kko >> 3;
    bf16x8 av[4], bv[4];
    #pragma unroll
    for (int qi = 0; qi < 4; ++qi)
      av[qi] = *(const bf16x8*)(lq + swz64(qi*16 + llo, kc + lhi));
    #pragma unroll
    for (int nj = 0; nj < 4; ++nj)
      bv[nj] = *(const bf16x8*)(KL + swz64(nj*16 + llo, kc + lhi));
    #pragma unroll
    for (int qi = 0; qi < 4; ++qi)
      #pragma unroll
      for (int nj = 0; nj < 4; ++nj)
        s[qi][nj] = mfma16(av[qi], bv[nj], s[qi][nj]);
  }
  float rcp_[4][4];
  #pragma unroll
  for (int qi = 0; qi < 4; ++qi) {
    float mx[4] = {-1e30f, -1e30f, -1e30f, -1e30f};
    #pragma unroll
    for (int nj = 0; nj < 4; ++nj)
      #pragma unroll
      for (int r = 0; r < 4; ++r) {
        float z = s[qi][nj][r] * 0.125f;
        s[qi][nj][r] = z;
        mx[r] = fmaxf(mx[r], z);
      }
    #pragma unroll
    for (int r = 0; r < 4; ++r) {
      float m = mx[r];
      m = fmaxf(m, __shfl_xor(m, 1)); m = fmaxf(m, __shfl_xor(m, 2));
      m = fmaxf(m, __shfl_xor(m, 4)); m = fmaxf(m, __shfl_xor(m, 8));
      mx[r] = m;
    }
    float rs[4] = {0.f, 0.f, 0.f, 0.f};
    #pragma unroll
    for (int nj = 0; nj < 4; ++nj)
      #pragma unroll
      for (int r = 0; r < 4; ++r) {
        float p = __expf(s[qi][nj][r] - mx[r]);
        rs[r] += p;
        const int prow = qi*16 + lhi*4 + r, pcol = nj*16 + llo;
        lp[swz64(prow, pcol >> 3) + (pcol & 7)] = f2b(p);
      }
    #pragma unroll
    for (int r = 0; r < 4; ++r) {
      float v = rs[r];
      v += __shfl_xor(v, 1); v += __shfl_xor(v, 2);
      v += __shfl_xor(v, 4); v += __shfl_xor(v, 8);
      rcp_[qi][r] = 1.0f / v;
    }
  }
  LGKM0;
  f32x4 o[4][4];
  #pragma unroll
  for (int qi = 0; qi < 4; ++qi)
    #pragma unroll
    for (int dj = 0; dj < 4; ++dj) o[qi][dj] = f32x4{0.f,0.f,0.f,0.f};
  #pragma unroll
  for (int kko = 0; kko < 64; kko += 32) {
    const int kc = kko >> 3;
    bf16x8 pa[4], tb[4];
    #pragma unroll
    for (int qi = 0; qi < 4; ++qi)
      pa[qi] = *(const bf16x8*)(lp + swz64(qi*16 + llo, kc + lhi));
    #pragma unroll
    for (int dj = 0; dj < 4; ++dj)
      tb[dj] = *(const bf16x8*)(T2 + swz64(dj*16 + llo, kc + lhi));
    #pragma unroll
    for (int qi = 0; qi < 4; ++qi)
      #pragma unroll
      for (int dj = 0; dj < 4; ++dj)
        o[qi][dj] = mfma16(pa[qi], tb[dj], o[qi][dj]);
  }
  #pragma unroll
  for (int qi = 0; qi < 4; ++qi)
    #pragma unroll
    for (int dj = 0; dj < 4; ++dj)
      #pragma unroll
      for (int r = 0; r < 4; ++r) {
        int n = n0 + qi*16 + lhi*4 + r;
        oatt[((size_t)b*8192 + n)*512 + h*64 + dj*16 + llo] = f2b(o[qi][dj][r] * rcp_[qi][r]);
      }
}

// ---------------- launch ----------------
extern "C" void kernel_launch(void* const* d_in, const int* in_sizes, int n_in,
                              void* d_out, int out_size, void* d_ws, size_t ws_size,
                              hipStream_t stream) {
  const float* x      = (const float*)d_in[0];
  const float* qkv_w  = (const float*)d_in[1];
  const float* qkv_b  = (const float*)d_in[2];
  const float* proj_w = (const float*)d_in[3];
  const float* proj_b = (const float*)d_in[4];
  float* out = (float*)d_out;

  char* ws = (char*)d_ws;
  size_t off = 0;
  auto alloc = [&](size_t bytes) -> char* {
    char* p = ws + off;
    off += (bytes + 255) & ~(size_t)255;
    return p;
  };
  u16*   x_bf  = (u16*)  alloc(33554432);   // x bf16; reused as out_att after GEMM1
  u16*   vt    = (u16*)  alloc(33554432);   // v^T bf16 [BH][64][8192]
  u16*   wqkvt = (u16*)  alloc(1572864);    // qkv_w^T bf16 [1536][512]
  u16*   wprjt = (u16*)  alloc(524288);     // proj_w^T bf16 [512][512]
  float* qlf   = (float*)alloc(524288);     // q_l f32 [BH][64][64]
  float* klf   = (float*)alloc(524288);
  u16*   qlb   = (u16*)  alloc(262144);     // bf16 copies
  u16*   klb   = (u16*)  alloc(262144);
  float* nump  = (float*)alloc(16777216);   // t1 numerator partials [BH][32][64][64]
  float* denp  = (float*)alloc(262144);     // denominator partials  [BH][32][64]
  float* t2t   = (float*)alloc(524288);     // t2^T f32 [BH][64][64]
  float* t1g   = (float*)alloc(524288);     // T1 f32 [BH][64][64]
  float* invg  = (float*)alloc(524288);     // K2^-1 f32 [BH][64][64]
  if (off > ws_size) return;                // insufficient scratch -> fail loudly

  u16* qm   = (u16*)d_out;                  // q bf16 [BH][8192][64] (dead before proj writes)
  u16* kmat = qm + 16777216;                // k bf16
  u16* oatt = x_bf;                         // out_att bf16 [B][N][C]

  k_cast_x<<<8192, 256, 0, stream>>>((const float4*)x, (uint4*)x_bf, 2097152);
  k_tcast<<<3072, 256, 0, stream>>>(qkv_w, wqkvt, 512, 1536);
  k_tcast<<<1024, 256, 0, stream>>>(proj_w, wprjt, 512, 512);
  k_lmk<<<256, 256, 0, stream>>>(x, qkv_w, qkv_b, qlf, klf, qlb, klb);
  // fused: 3072 gemm blocks + 32 inversion blocks (wgid<32, dispatched first)
  k_gemm<0><<<3104, 256, 0, stream>>>(x_bf, wqkvt, qkv_b, 512, 12, qm, kmat, vt,
                                      nullptr, 0, qlf, klf, invg);
  k_flash3<<<256, 256, 0, stream>>>(qlb, kmat, vt, nump, denp);
  k_t1<<<128, 256, 0, stream>>>(nump, denp, t1g);
  k_t2<<<32, 256, 0, stream>>>(invg, t1g, t2t);
  k_flash1<<<1024, 256, 0, stream>>>(qm, klb, t2t, oatt);
  k_gemm<1><<<1024, 256, 0, stream>>>(oatt, wprjt, proj_b, 512, 4, nullptr, nullptr,
                                      nullptr, out, 512, nullptr, nullptr, nullptr);
}

// Round 17
// 315.209 us; speedup vs baseline: 1.0622x; 1.0622x over previous
//
#include <hip/hip_runtime.h>
#include <stdint.h>

using bf16x8 = __attribute__((ext_vector_type(8))) short;
using bf16x8_t = __attribute__((ext_vector_type(8))) __bf16;
using f32x4  = __attribute__((ext_vector_type(4))) float;
typedef unsigned short u16;
typedef unsigned int   u32;

#define DEVI static __device__ __forceinline__

typedef u32 __attribute__((address_space(1))) gu32;
typedef u32 __attribute__((address_space(3))) lu32;

DEVI u16 f2b(float f) {
  union { float f; u32 u; } v; v.f = f;
  u32 r = v.u + 0x7FFFu + ((v.u >> 16) & 1u);
  return (u16)(r >> 16);
}

DEVI f32x4 mfma16(bf16x8 a, bf16x8 b, f32x4 c) {
  return __builtin_amdgcn_mfma_f32_16x16x32_bf16(
      __builtin_bit_cast(bf16x8_t, a), __builtin_bit_cast(bf16x8_t, b), c, 0, 0, 0);
}

DEVI void gload16(const void* g, void* l) {
  __builtin_amdgcn_global_load_lds((const gu32*)(uintptr_t)g,
                                   (lu32*)(u32)(uintptr_t)l, 16, 0, 0);
}

// XOR-swizzled u16 index of 16B chunk `ch` (0..7) in row `row` of a [*][64] u16
// tile (phys chunk = logical chunk ^ (row&7)). DMA staging keeps LDS linear and
// pre-swizzles the GLOBAL source chunk instead (guide rule #21).
DEVI int swz64(int row, int ch) { return row*64 + ((ch ^ (row & 7)) << 3); }

// Swizzled addressing for the inversion branch's [64][128] f32 matrix (exactly
// 32768B, no pad). Physical float4 slot = logical ^ (row&31): per-lane own-row
// accesses conflict-free, same-slot broadcasts free.
DEVI int a4x(int row, int s4) { return row*32 + (s4 ^ (row & 31)); }           // float4 units
DEVI int awx(int row, int wd) { return row*128 + (((wd >> 2) ^ (row & 31)) << 2) + (wd & 3); } // f32 units

#define VMCNT0 asm volatile("s_waitcnt vmcnt(0)" ::: "memory")
#define LGKM0  asm volatile("s_waitcnt lgkmcnt(0)" ::: "memory")

// ---------------- casts ----------------
__global__ void __launch_bounds__(256) k_cast_x(const float4* __restrict__ xin,
                                                uint4* __restrict__ xo, int n8) {
  int i = blockIdx.x * 256 + threadIdx.x;
  if (i >= n8) return;
  float4 a = xin[2*i], b = xin[2*i+1];
  uint4 o;
  o.x = ((u32)f2b(a.y) << 16) | f2b(a.x);
  o.y = ((u32)f2b(a.w) << 16) | f2b(a.z);
  o.z = ((u32)f2b(b.y) << 16) | f2b(b.x);
  o.w = ((u32)f2b(b.w) << 16) | f2b(b.z);
  xo[i] = o;
}

// w [R][Cc] f32 -> wt [Cc][R] bf16
__global__ void __launch_bounds__(256) k_tcast(const float* __restrict__ w,
                                               u16* __restrict__ wt, int R, int Cc) {
  int o = blockIdx.x * 256 + threadIdx.x;
  if (o >= R * Cc) return;
  int c = o % R, j = o / R;
  wt[o] = f2b(w[(size_t)c * Cc + j]);
}

// ---------------- exact f32 landmark q_l / k_l ----------------
__global__ void __launch_bounds__(256) k_lmk(
    const float* __restrict__ x, const float* __restrict__ w,
    const float* __restrict__ bias, float* __restrict__ qlf,
    float* __restrict__ klf, u16* __restrict__ qlb, u16* __restrict__ klb) {
  __shared__ __align__(16) float xr[512];
  const int t = threadIdx.x;
  const int b = blockIdx.x >> 6, i = blockIdx.x & 63;
  const int idx = (i * 8191) / 63;   // == np.linspace(0,8191,64).astype(int32)
  const float4* xg = (const float4*)(x + ((size_t)b*8192 + idx)*512);
  if (t < 128) ((float4*)xr)[t] = xg[t];
  __syncthreads();

  const int o0 = t << 2;
  float4 acc = *(const float4*)(bias + o0);
  const float* wp = w + o0;
  #pragma unroll 8
  for (int c = 0; c < 512; ++c) {
    const float xv = xr[c];
    const float4 wv = *(const float4*)(wp + (size_t)c*1536);
    acc.x = fmaf(xv, wv.x, acc.x); acc.y = fmaf(xv, wv.y, acc.y);
    acc.z = fmaf(xv, wv.z, acc.z); acc.w = fmaf(xv, wv.w, acc.w);
  }

  const int h = (o0 >> 6) & 7, d = o0 & 63;
  const size_t ofs = ((size_t)(b*8 + h)*64 + i)*64 + d;
  ushort4 pk;
  pk.x = f2b(acc.x); pk.y = f2b(acc.y); pk.z = f2b(acc.z); pk.w = f2b(acc.w);
  if (o0 < 512) { *(float4*)(qlf + ofs) = acc; *(ushort4*)(qlb + ofs) = pk; }
  else          { *(float4*)(klf + ofs) = acc; *(ushort4*)(klb + ofs) = pk; }
}

// ---------------- fused K2 softmax + SINGLE-WAVE Gauss-Jordan inverse ----------------
// r16 established: zero-barrier single-wave GJ with a4x swizzle gives VGPR=88
// (gemm-level) and ~0 conflicts, but r16's `unroll 1` on the rank-1 update
// serialized the LDS chain (~3.8k cyc/col -> 210us). r17: unroll 4 restores
// ILP (4 read-pairs in flight) -> ~1k cyc/col, ~27us standalone.
__device__ __noinline__ void inv_body(
    char* smem, const float* __restrict__ qlf, const float* __restrict__ klf,
    float* __restrict__ invg, int bh, int l) {
  float* Am = (float*)smem;
  float4* A4 = (float4*)smem;

  // stage k_l into right half (coalesced global reads, swizzled LDS writes)
  const float4* kg = (const float4*)(klf + (size_t)bh*4096);
  #pragma unroll 4
  for (int g = l; g < 1024; g += 64)
    A4[a4x(g >> 4, 16 + (g & 15))] = kg[g];
  LGKM0; asm volatile("" ::: "memory");

  // logits row l -> left half: Am[l][j] = (q_l[l].k_l[j]) * 0.125
  const float4* qg = (const float4*)(qlf + (size_t)bh*4096) + (size_t)l*16;
  #pragma unroll 1
  for (int jb = 0; jb < 4; ++jb) {
    float acc[16];
    #pragma unroll
    for (int jj = 0; jj < 16; ++jj) acc[jj] = 0.f;
    #pragma unroll 1
    for (int ch = 0; ch < 4; ++ch) {
      float4 qc[4];
      #pragma unroll
      for (int i = 0; i < 4; ++i) qc[i] = qg[ch*4 + i];
      #pragma unroll
      for (int jj = 0; jj < 16; ++jj) {
        const int j = jb*16 + jj;
        float a = acc[jj];
        #pragma unroll
        for (int i = 0; i < 4; ++i) {
          float4 kv = A4[a4x(j, 16 + ch*4 + i)];
          a = fmaf(qc[i].x, kv.x, a); a = fmaf(qc[i].y, kv.y, a);
          a = fmaf(qc[i].z, kv.z, a); a = fmaf(qc[i].w, kv.w, a);
        }
        acc[jj] = a;
      }
    }
    #pragma unroll
    for (int jj = 0; jj < 16; ++jj)
      Am[awx(l, jb*16 + jj)] = acc[jj] * 0.125f;
  }

  // softmax of own row (lane-local float4 passes) + identity augment
  float mr = -1e30f;
  #pragma unroll 4
  for (int i = 0; i < 16; ++i) {
    float4 v = A4[a4x(l, i)];
    mr = fmaxf(mr, fmaxf(fmaxf(v.x, v.y), fmaxf(v.z, v.w)));
  }
  float sr = 0.f;
  #pragma unroll 4
  for (int i = 0; i < 16; ++i) {
    float4 v = A4[a4x(l, i)];
    v.x = __expf(v.x - mr); v.y = __expf(v.y - mr);
    v.z = __expf(v.z - mr); v.w = __expf(v.w - mr);
    sr += v.x + v.y + v.z + v.w;
    A4[a4x(l, i)] = v;
  }
  const float rinv = 1.f / sr;
  #pragma unroll 4
  for (int i = 0; i < 16; ++i) {
    float4 v = A4[a4x(l, i)];
    v.x *= rinv; v.y *= rinv; v.z *= rinv; v.w *= rinv;
    A4[a4x(l, i)] = v;
    float4 e = {0.f, 0.f, 0.f, 0.f};
    const int base = i*4;
    if (base     == l) e.x = 1.f;
    if (base + 1 == l) e.y = 1.f;
    if (base + 2 == l) e.z = 1.f;
    if (base + 3 == l) e.w = 1.f;
    A4[a4x(l, 16 + i)] = e;
  }
  LGKM0; asm volatile("" ::: "memory");

  // Gauss-Jordan, barrier-free: virtual pivot, no normalize
  int used = 0, mypivc = 0;
  #pragma unroll 1
  for (int c = 0; c < 64; ++c) {
    const float ac = Am[awx(l, c)];
    float val = used ? -1.f : fabsf(ac);
    int idx = l;
    #pragma unroll
    for (int mk = 1; mk < 64; mk <<= 1) {
      float ov = __shfl_xor(val, mk);
      int oi = __shfl_xor(idx, mk);
      int take = (ov > val) || (ov == val && oi < idx);
      val = take ? ov : val;
      idx = take ? oi : idx;
    }
    const int p = idx;                       // uniform across lanes
    if (l == p) { used = 1; mypivc = c; }
    const float coef = -ac / Am[awx(p, c)];  // broadcast LDS read
    if (l != p) {
      #pragma unroll 4
      for (int s4 = c >> 2; s4 < 32; ++s4) { // slots < c>>2: pivot row is 0 there
        float4 a = A4[a4x(l, s4)];
        float4 pv = A4[a4x(p, s4)];          // broadcast
        a.x = fmaf(coef, pv.x, a.x); a.y = fmaf(coef, pv.y, a.y);
        a.z = fmaf(coef, pv.z, a.z); a.w = fmaf(coef, pv.w, a.w);
        A4[a4x(l, s4)] = a;
      }
    }
    LGKM0; asm volatile("" ::: "memory");    // updates visible before next scan
  }

  // extraction: lane l holds row mypivc of the inverse; divide by final diag
  const float rd = 1.f / Am[awx(l, mypivc)];
  float4* og = (float4*)(invg + (size_t)bh*4096 + (size_t)mypivc*64);
  #pragma unroll 4
  for (int i = 0; i < 16; ++i) {
    float4 v = A4[a4x(l, 16 + i)];
    v.x *= rd; v.y *= rd; v.z *= rd; v.w *= rd;
    og[i] = v;
  }
}

// ---------------- 128x128 tile bf16 MFMA GEMM (A[M][K] @ Bt[N][K]^T) ----------------
// MODE 0: qkv epilogue + 32 fused K2-inversion blocks (wgid<32: wave0 runs the
// barrier-free single-wave inverse, waves 1-3 exit).
// MODE 1: f32 epilogue (out[M][Nout] = acc + bias), no fusion.
template <int MODE>
__global__ void __launch_bounds__(256) k_gemm(
    const u16* __restrict__ A, const u16* __restrict__ Bt,
    const float* __restrict__ bias, int K, int ntn,
    u16* __restrict__ qdst, u16* __restrict__ kdst, u16* __restrict__ vtdst,
    float* __restrict__ fout, int Nout,
    const float* __restrict__ qlf, const float* __restrict__ klf,
    float* __restrict__ invg) {
  __shared__ __align__(16) char smem[32768];
  const int t = threadIdx.x;
  // XCD swizzle: gridDim.x % 8 == 0 for all call sites -> bijective
  const int cpx = gridDim.x >> 3;
  const int wgid = (blockIdx.x & 7) * cpx + (blockIdx.x >> 3);

  if (MODE == 0 && wgid < 32) {
    if (t < 64) inv_body(smem, qlf, klf, invg, wgid, t);
    return;
  }

  // ======== GEMM path ========
  u16* As = (u16*)smem;
  u16* Bs = (u16*)(smem + 16384);
  const int wg2 = wgid - (MODE == 0 ? 32 : 0);
  const int tn = wg2 % ntn, tm = wg2 / ntn;
  const int m0 = tm << 7, n0 = tn << 7;
  const int w = t >> 6, l = t & 63;
  const int wr = (w >> 1) << 6, wc = (w & 1) << 6;
  const int lhi = l >> 4, llo = l & 15;

  f32x4 acc[4][4];
  #pragma unroll
  for (int i = 0; i < 4; ++i)
    #pragma unroll
    for (int j = 0; j < 4; ++j) acc[i][j] = f32x4{0.f,0.f,0.f,0.f};

  // staged rows advance by 32 (≡0 mod 8), so row&7 == (t>>3)&7 for all i
  const int csw = (((t & 7) ^ ((t >> 3) & 7)) << 3);
  const u16* ga = A  + (size_t)(m0 + (t >> 3)) * K + csw;
  const u16* gb = Bt + (size_t)(n0 + (t >> 3)) * K + csw;
  u16* lA = As + (w << 9);
  u16* lB = Bs + (w << 9);

  for (int kt = 0; kt < K; kt += 64) {
    __syncthreads();
    #pragma unroll
    for (int i = 0; i < 4; ++i) {
      gload16(ga + (size_t)(i*32)*K + kt, lA + i*2048);
      gload16(gb + (size_t)(i*32)*K + kt, lB + i*2048);
    }
    VMCNT0;
    __syncthreads();
    #pragma unroll
    for (int kko = 0; kko < 64; kko += 32) {
      const int kc = kko >> 3;     // chunk base: 0 or 4
      bf16x8 av[4], bv[4];
      #pragma unroll
      for (int mi = 0; mi < 4; ++mi)
        av[mi] = *(const bf16x8*)(As + swz64(wr + mi*16 + llo, kc + lhi));
      #pragma unroll
      for (int ni = 0; ni < 4; ++ni)
        bv[ni] = *(const bf16x8*)(Bs + swz64(wc + ni*16 + llo, kc + lhi));
      #pragma unroll
      for (int mi = 0; mi < 4; ++mi)
        #pragma unroll
        for (int ni = 0; ni < 4; ++ni)
          acc[mi][ni] = mfma16(av[mi], bv[ni], acc[mi][ni]);
    }
  }

  #pragma unroll
  for (int ni = 0; ni < 4; ++ni) {
    const int gcol = n0 + wc + ni*16 + llo;
    const float bvv = bias[gcol];
    if (MODE == 0) {
      const int tt = gcol >> 9, h = (gcol >> 6) & 7, d = gcol & 63;
      #pragma unroll
      for (int mi = 0; mi < 4; ++mi) {
        const int grow = m0 + wr + mi*16 + (lhi << 2);
        const int b = grow >> 13, n = grow & 8191;
        const size_t bh = (size_t)(b*8 + h);
        if (tt == 2) {
          ushort4 pk;
          pk.x = f2b(acc[mi][ni][0] + bvv); pk.y = f2b(acc[mi][ni][1] + bvv);
          pk.z = f2b(acc[mi][ni][2] + bvv); pk.w = f2b(acc[mi][ni][3] + bvv);
          *(ushort4*)(vtdst + (bh*64 + d)*8192 + n) = pk;
        } else {
          u16* dst = (tt == 0 ? qdst : kdst) + (bh*8192 + n)*64 + d;
          #pragma unroll
          for (int r = 0; r < 4; ++r) dst[(size_t)r*64] = f2b(acc[mi][ni][r] + bvv);
        }
      }
    } else {
      #pragma unroll
      for (int mi = 0; mi < 4; ++mi) {
        const int grow = m0 + wr + mi*16 + (lhi << 2);
        #pragma unroll
        for (int r = 0; r < 4; ++r)
          fout[(size_t)(grow + r)*Nout + gcol] = acc[mi][ni][r] + bvv;
      }
    }
  }
}

// ---------------- kernel_3 partials: num = sum_n e^{q_l.k/8} v, den = sum_n e^{...} ----------------
__global__ void __launch_bounds__(256) k_flash3(
    const u16* __restrict__ qlb, const u16* __restrict__ kmat,
    const u16* __restrict__ vt, float* __restrict__ num_part,
    float* __restrict__ den_part) {
  __shared__ __align__(16) u16 QL[64*64];
  __shared__ __align__(16) u16 KT[4][64*64];
  __shared__ __align__(16) u16 VT[4][64*64];
  __shared__ __align__(16) u16 PL[4][64*64];
  const int t = threadIdx.x, w = t >> 6, l = t & 63;
  const int bh = blockIdx.x >> 3, split = blockIdx.x & 7;
  const int lhi = l >> 4, llo = l & 15;
  const int csw = ((l & 7) ^ (l >> 3)) << 3;       // source chunk pre-swizzle

  #pragma unroll
  for (int i = 0; i < 2; ++i)
    gload16(qlb + (size_t)bh*4096 + (size_t)((i*256 + (t & ~7)) << 3)
                + (((t & 7) ^ ((t >> 3) & 7)) << 3),
            QL + i*2048 + (w << 9));
  VMCNT0;
  __syncthreads();

  f32x4 oacc[4][4];
  float dacc[4][4];
  #pragma unroll
  for (int a = 0; a < 4; ++a)
    #pragma unroll
    for (int bq = 0; bq < 4; ++bq) { oacc[a][bq] = f32x4{0.f,0.f,0.f,0.f}; dacc[a][bq] = 0.f; }

  const int nb = split << 10;
  u16* lk = KT[w]; u16* lv = VT[w]; u16* lp = PL[w];
  for (int j = 0; j < 4; ++j) {
    const int n0 = nb + ((w + 4*j) << 6);
    const u16* gk = kmat + ((size_t)bh*8192 + n0 + (l >> 3))*64 + csw;
    const u16* gv = vt   + ((size_t)bh*64 + (l >> 3))*8192 + n0 + csw;
    asm volatile("" ::: "memory");
    LGKM0;   // drain prior iter's ds_reads before DMA overwrites lk/lv
    #pragma unroll
    for (int i = 0; i < 8; ++i) {
      gload16(gk + (size_t)(i*8)*64, lk + i*512);
      gload16(gv + (size_t)(i*8)*8192, lv + i*512);
    }
    VMCNT0;

    f32x4 s[4][4];
    #pragma unroll
    for (int qi = 0; qi < 4; ++qi)
      #pragma unroll
      for (int nj = 0; nj < 4; ++nj) s[qi][nj] = f32x4{0.f,0.f,0.f,0.f};
    #pragma unroll
    for (int kko = 0; kko < 64; kko += 32) {
      const int kc = kko >> 3;
      bf16x8 av[4], bv[4];
      #pragma unroll
      for (int qi = 0; qi < 4; ++qi)
        av[qi] = *(const bf16x8*)(QL + swz64(qi*16 + llo, kc + lhi));
      #pragma unroll
      for (int nj = 0; nj < 4; ++nj)
        bv[nj] = *(const bf16x8*)(lk + swz64(nj*16 + llo, kc + lhi));
      #pragma unroll
      for (int qi = 0; qi < 4; ++qi)
        #pragma unroll
        for (int nj = 0; nj < 4; ++nj)
          s[qi][nj] = mfma16(av[qi], bv[nj], s[qi][nj]);
    }
    #pragma unroll
    for (int qi = 0; qi < 4; ++qi) {
      float rs[4] = {0.f, 0.f, 0.f, 0.f};
      #pragma unroll
      for (int nj = 0; nj < 4; ++nj)
        #pragma unroll
        for (int r = 0; r < 4; ++r) {
          float p = __expf(s[qi][nj][r] * 0.125f);  // logits bounded, no max needed
          rs[r] += p;
          const int prow = qi*16 + lhi*4 + r, pcol = nj*16 + llo;
          lp[swz64(prow, pcol >> 3) + (pcol & 7)] = f2b(p);
        }
      #pragma unroll
      for (int r = 0; r < 4; ++r) {
        float v = rs[r];
        v += __shfl_xor(v, 1); v += __shfl_xor(v, 2);
        v += __shfl_xor(v, 4); v += __shfl_xor(v, 8);
        dacc[qi][r] += v;
      }
    }
    LGKM0;
    #pragma unroll
    for (int kko = 0; kko < 64; kko += 32) {
      const int kc = kko >> 3;
      bf16x8 pa[4], vb[4];
      #pragma unroll
      for (int qi = 0; qi < 4; ++qi)
        pa[qi] = *(const bf16x8*)(lp + swz64(qi*16 + llo, kc + lhi));
      #pragma unroll
      for (int dj = 0; dj < 4; ++dj)
        vb[dj] = *(const bf16x8*)(lv + swz64(dj*16 + llo, kc + lhi));
      #pragma unroll
      for (int qi = 0; qi < 4; ++qi)
        #pragma unroll
        for (int dj = 0; dj < 4; ++dj)
          oacc[qi][dj] = mfma16(pa[qi], vb[dj], oacc[qi][dj]);
    }
  }
  const int sw = (split << 2) + w;
  float* np = num_part + ((size_t)bh*32 + sw)*4096;
  #pragma unroll
  for (int qi = 0; qi < 4; ++qi)
    #pragma unroll
    for (int dj = 0; dj < 4; ++dj)
      #pragma unroll
      for (int r = 0; r < 4; ++r)
        np[(qi*16 + lhi*4 + r)*64 + dj*16 + llo] = oacc[qi][dj][r];
  if (llo == 0) {
    float* dp = den_part + ((size_t)bh*32 + sw)*64;
    #pragma unroll
    for (int qi = 0; qi < 4; ++qi)
      #pragma unroll
      for (int r = 0; r < 4; ++r)
        dp[qi*16 + lhi*4 + r] = dacc[qi][r];
  }
}

// ---------------- T1 = (sum_s num_part) / den : wide reduce ----------------
__global__ void __launch_bounds__(256) k_t1(
    const float* __restrict__ num_part, const float* __restrict__ den_part,
    float* __restrict__ t1g) {
  const int t = threadIdx.x;
  const int bh = blockIdx.x >> 2, ch = blockIdx.x & 3;
  const int f = ch*256 + t;                 // float4 index in [0,1024)
  const int m = f >> 4;                     // landmark row
  const float4* ng = (const float4*)num_part + (size_t)bh*32*1024;
  float4 acc = {0.f, 0.f, 0.f, 0.f};
  float ds = 0.f;
  for (int s = 0; s < 32; ++s) {
    float4 v = ng[(size_t)s*1024 + f];
    acc.x += v.x; acc.y += v.y; acc.z += v.z; acc.w += v.w;
    ds += den_part[((size_t)bh*32 + s)*64 + m];
  }
  float r = 1.f / ds;
  acc.x *= r; acc.y *= r; acc.z *= r; acc.w *= r;
  ((float4*)t1g)[(size_t)bh*1024 + f] = acc;
}

// ---------------- t2^T = (Inv @ T1)^T ----------------
__global__ void __launch_bounds__(256) k_t2(
    const float* __restrict__ invg, const float* __restrict__ t1g,
    float* __restrict__ t2t) {
  __shared__ __align__(16) float IV[64*68];
  __shared__ __align__(16) float T1[64*68];
  const int t = threadIdx.x;
  const int bh = blockIdx.x;
  const int i4 = t >> 2, jc = t & 3;
  float4* IV4 = (float4*)IV;
  float4* T14 = (float4*)T1;
  const float4* ig = (const float4*)(invg + (size_t)bh*4096);
  const float4* tg = (const float4*)(t1g + (size_t)bh*4096);
  #pragma unroll
  for (int k = 0; k < 4; ++k) {
    int g = k*256 + t, row = g >> 4, c4 = g & 15;
    IV4[row*17 + c4] = ig[g];
    T14[row*17 + c4] = tg[g];
  }
  __syncthreads();
  float acc[16];
  #pragma unroll
  for (int d = 0; d < 16; ++d) acc[d] = 0.f;
  for (int m = 0; m < 64; ++m) {
    float wv = IV[i4*68 + m];
    #pragma unroll
    for (int d4 = 0; d4 < 4; ++d4) {
      float4 tv = T14[m*17 + jc*4 + d4];
      acc[d4*4+0] = fmaf(wv, tv.x, acc[d4*4+0]);
      acc[d4*4+1] = fmaf(wv, tv.y, acc[d4*4+1]);
      acc[d4*4+2] = fmaf(wv, tv.z, acc[d4*4+2]);
      acc[d4*4+3] = fmaf(wv, tv.w, acc[d4*4+3]);
    }
  }
  #pragma unroll
  for (int dd = 0; dd < 16; ++dd) {
    int d = jc*16 + dd;
    t2t[((size_t)bh*64 + d)*64 + i4] = acc[dd];
  }
}

// ---------------- fused kernel_1 softmax + @t2 -> out_att bf16 [B][N][C] ----------------
__global__ void __launch_bounds__(256) k_flash1(
    const u16* __restrict__ q, const u16* __restrict__ klb,
    const float* __restrict__ t2t, u16* __restrict__ oatt) {
  __shared__ __align__(16) u16 KL[64*64];
  __shared__ __align__(16) u16 T2[64*64];
  __shared__ __align__(16) u16 QT[4][64*64];
  __shared__ __align__(16) u16 PL[4][64*64];
  const int t = threadIdx.x, w = t >> 6, l = t & 63;
  const int bh = blockIdx.x >> 5, blk = blockIdx.x & 31;
  const int lhi = l >> 4, llo = l & 15;
  const int b = bh >> 3, h = bh & 7;
  const int csw = ((l & 7) ^ (l >> 3)) << 3;

  #pragma unroll
  for (int i = 0; i < 2; ++i)
    gload16(klb + (size_t)bh*4096 + (size_t)((i*256 + (t & ~7)) << 3)
                + (((t & 7) ^ ((t >> 3) & 7)) << 3),
            KL + i*2048 + (w << 9));
  for (int i = t; i < 4096; i += 256)
    T2[swz64(i >> 6, (i & 63) >> 3) + (i & 7)] = f2b(t2t[(size_t)bh*4096 + i]);
  VMCNT0;
  __syncthreads();

  const int n0 = (blk << 8) + (w << 6);
  const u16* gq = q + ((size_t)bh*8192 + n0 + (l >> 3))*64 + csw;
  u16* lq = QT[w]; u16* lp = PL[w];
  #pragma unroll
  for (int i = 0; i < 8; ++i) gload16(gq + (size_t)(i*8)*64, lq + i*512);
  VMCNT0;

  f32x4 s[4][4];
  #pragma unroll
  for (int qi = 0; qi < 4; ++qi)
    #pragma unroll
    for (int nj = 0; nj < 4; ++nj) s[qi][nj] = f32x4{0.f,0.f,0.f,0.f};
  #pragma unroll
  for (int kko = 0; kko < 64; kko += 32) {
    const int kc = kko >> 3;
    bf16x8 av[4], bv[4];
    #pragma unroll
    for (int qi = 0; qi < 4; ++qi)
      av[qi] = *(const bf16x8*)(lq + swz64(qi*16 + llo, kc + lhi));
    #pragma unroll
    for (int nj = 0; nj < 4; ++nj)
      bv[nj] = *(const bf16x8*)(KL + swz64(nj*16 + llo, kc + lhi));
    #pragma unroll
    for (int qi = 0; qi < 4; ++qi)
      #pragma unroll
      for (int nj = 0; nj < 4; ++nj)
        s[qi][nj] = mfma16(av[qi], bv[nj], s[qi][nj]);
  }
  float rcp_[4][4];
  #pragma unroll
  for (int qi = 0; qi < 4; ++qi) {
    float mx[4] = {-1e30f, -1e30f, -1e30f, -1e30f};
    #pragma unroll
    for (int nj = 0; nj < 4; ++nj)
      #pragma unroll
      for (int r = 0; r < 4; ++r) {
        float z = s[qi][nj][r] * 0.125f;
        s[qi][nj][r] = z;
        mx[r] = fmaxf(mx[r], z);
      }
    #pragma unroll
    for (int r = 0; r < 4; ++r) {
      float m = mx[r];
      m = fmaxf(m, __shfl_xor(m, 1)); m = fmaxf(m, __shfl_xor(m, 2));
      m = fmaxf(m, __shfl_xor(m, 4)); m = fmaxf(m, __shfl_xor(m, 8));
      mx[r] = m;
    }
    float rs[4] = {0.f, 0.f, 0.f, 0.f};
    #pragma unroll
    for (int nj = 0; nj < 4; ++nj)
      #pragma unroll
      for (int r = 0; r < 4; ++r) {
        float p = __expf(s[qi][nj][r] - mx[r]);
        rs[r] += p;
        const int prow = qi*16 + lhi*4 + r, pcol = nj*16 + llo;
        lp[swz64(prow, pcol >> 3) + (pcol & 7)] = f2b(p);
      }
    #pragma unroll
    for (int r = 0; r < 4; ++r) {
      float v = rs[r];
      v += __shfl_xor(v, 1); v += __shfl_xor(v, 2);
      v += __shfl_xor(v, 4); v += __shfl_xor(v, 8);
      rcp_[qi][r] = 1.0f / v;
    }
  }
  LGKM0;
  f32x4 o[4][4];
  #pragma unroll
  for (int qi = 0; qi < 4; ++qi)
    #pragma unroll
    for (int dj = 0; dj < 4; ++dj) o[qi][dj] = f32x4{0.f,0.f,0.f,0.f};
  #pragma unroll
  for (int kko = 0; kko < 64; kko += 32) {
    const int kc = kko >> 3;
    bf16x8 pa[4], tb[4];
    #pragma unroll
    for (int qi = 0; qi < 4; ++qi)
      pa[qi] = *(const bf16x8*)(lp + swz64(qi*16 + llo, kc + lhi));
    #pragma unroll
    for (int dj = 0; dj < 4; ++dj)
      tb[dj] = *(const bf16x8*)(T2 + swz64(dj*16 + llo, kc + lhi));
    #pragma unroll
    for (int qi = 0; qi < 4; ++qi)
      #pragma unroll
      for (int dj = 0; dj < 4; ++dj)
        o[qi][dj] = mfma16(pa[qi], tb[dj], o[qi][dj]);
  }
  #pragma unroll
  for (int qi = 0; qi < 4; ++qi)
    #pragma unroll
    for (int dj = 0; dj < 4; ++dj)
      #pragma unroll
      for (int r = 0; r < 4; ++r) {
        int n = n0 + qi*16 + lhi*4 + r;
        oatt[((size_t)b*8192 + n)*512 + h*64 + dj*16 + llo] = f2b(o[qi][dj][r] * rcp_[qi][r]);
      }
}

// ---------------- launch ----------------
extern "C" void kernel_launch(void* const* d_in, const int* in_sizes, int n_in,
                              void* d_out, int out_size, void* d_ws, size_t ws_size,
                              hipStream_t stream) {
  const float* x      = (const float*)d_in[0];
  const float* qkv_w  = (const float*)d_in[1];
  const float* qkv_b  = (const float*)d_in[2];
  const float* proj_w = (const float*)d_in[3];
  const float* proj_b = (const float*)d_in[4];
  float* out = (float*)d_out;

  char* ws = (char*)d_ws;
  size_t off = 0;
  auto alloc = [&](size_t bytes) -> char* {
    char* p = ws + off;
    off += (bytes + 255) & ~(size_t)255;
    return p;
  };
  u16*   x_bf  = (u16*)  alloc(33554432);   // x bf16; reused as out_att after GEMM1
  u16*   vt    = (u16*)  alloc(33554432);   // v^T bf16 [BH][64][8192]
  u16*   wqkvt = (u16*)  alloc(1572864);    // qkv_w^T bf16 [1536][512]
  u16*   wprjt = (u16*)  alloc(524288);     // proj_w^T bf16 [512][512]
  float* qlf   = (float*)alloc(524288);     // q_l f32 [BH][64][64]
  float* klf   = (float*)alloc(524288);
  u16*   qlb   = (u16*)  alloc(262144);     // bf16 copies
  u16*   klb   = (u16*)  alloc(262144);
  float* nump  = (float*)alloc(16777216);   // t1 numerator partials [BH][32][64][64]
  float* denp  = (float*)alloc(262144);     // denominator partials  [BH][32][64]
  float* t2t   = (float*)alloc(524288);     // t2^T f32 [BH][64][64]
  float* t1g   = (float*)alloc(524288);     // T1 f32 [BH][64][64]
  float* invg  = (float*)alloc(524288);     // K2^-1 f32 [BH][64][64]
  if (off > ws_size) return;                // insufficient scratch -> fail loudly

  u16* qm   = (u16*)d_out;                  // q bf16 [BH][8192][64] (dead before proj writes)
  u16* kmat = qm + 16777216;                // k bf16
  u16* oatt = x_bf;                         // out_att bf16 [B][N][C]

  k_cast_x<<<8192, 256, 0, stream>>>((const float4*)x, (uint4*)x_bf, 2097152);
  k_tcast<<<3072, 256, 0, stream>>>(qkv_w, wqkvt, 512, 1536);
  k_tcast<<<1024, 256, 0, stream>>>(proj_w, wprjt, 512, 512);
  k_lmk<<<256, 256, 0, stream>>>(x, qkv_w, qkv_b, qlf, klf, qlb, klb);
  // fused: 3072 gemm blocks + 32 inversion blocks (wgid<32, dispatched first)
  k_gemm<0><<<3104, 256, 0, stream>>>(x_bf, wqkvt, qkv_b, 512, 12, qm, kmat, vt,
                                      nullptr, 0, qlf, klf, invg);
  k_flash3<<<256, 256, 0, stream>>>(qlb, kmat, vt, nump, denp);
  k_t1<<<128, 256, 0, stream>>>(nump, denp, t1g);
  k_t2<<<32, 256, 0, stream>>>(invg, t1g, t2t);
  k_flash1<<<1024, 256, 0, stream>>>(qm, klb, t2t, oatt);
  k_gemm<1><<<1024, 256, 0, stream>>>(oatt, wprjt, proj_b, 512, 4, nullptr, nullptr,
                                      nullptr, out, 512, nullptr, nullptr, nullptr);
}

// Round 18
// 273.084 us; speedup vs baseline: 1.2261x; 1.1543x over previous
//
#include <hip/hip_runtime.h>
#include <stdint.h>

using bf16x8 = __attribute__((ext_vector_type(8))) short;
using bf16x8_t = __attribute__((ext_vector_type(8))) __bf16;
using f32x4  = __attribute__((ext_vector_type(4))) float;
typedef unsigned short u16;
typedef unsigned int   u32;

#define DEVI static __device__ __forceinline__

typedef u32 __attribute__((address_space(1))) gu32;
typedef u32 __attribute__((address_space(3))) lu32;

DEVI u16 f2b(float f) {
  union { float f; u32 u; } v; v.f = f;
  u32 r = v.u + 0x7FFFu + ((v.u >> 16) & 1u);
  return (u16)(r >> 16);
}

DEVI f32x4 mfma16(bf16x8 a, bf16x8 b, f32x4 c) {
  return __builtin_amdgcn_mfma_f32_16x16x32_bf16(
      __builtin_bit_cast(bf16x8_t, a), __builtin_bit_cast(bf16x8_t, b), c, 0, 0, 0);
}

DEVI void gload16(const void* g, void* l) {
  __builtin_amdgcn_global_load_lds((const gu32*)(uintptr_t)g,
                                   (lu32*)(u32)(uintptr_t)l, 16, 0, 0);
}

// XOR-swizzled u16 index of 16B chunk `ch` (0..7) in row `row` of a [*][64] u16
// tile (phys chunk = logical chunk ^ (row&7)). DMA staging keeps LDS linear and
// pre-swizzles the GLOBAL source chunk instead (guide rule #21).
DEVI int swz64(int row, int ch) { return row*64 + ((ch ^ (row & 7)) << 3); }

#define VMCNT0 asm volatile("s_waitcnt vmcnt(0)" ::: "memory")
#define LGKM0  asm volatile("s_waitcnt lgkmcnt(0)" ::: "memory")

// ---------------- casts ----------------
__global__ void __launch_bounds__(256) k_cast_x(const float4* __restrict__ xin,
                                                uint4* __restrict__ xo, int n8) {
  int i = blockIdx.x * 256 + threadIdx.x;
  if (i >= n8) return;
  float4 a = xin[2*i], b = xin[2*i+1];
  uint4 o;
  o.x = ((u32)f2b(a.y) << 16) | f2b(a.x);
  o.y = ((u32)f2b(a.w) << 16) | f2b(a.z);
  o.z = ((u32)f2b(b.y) << 16) | f2b(b.x);
  o.w = ((u32)f2b(b.w) << 16) | f2b(b.z);
  xo[i] = o;
}

// w [R][Cc] f32 -> wt [Cc][R] bf16
__global__ void __launch_bounds__(256) k_tcast(const float* __restrict__ w,
                                               u16* __restrict__ wt, int R, int Cc) {
  int o = blockIdx.x * 256 + threadIdx.x;
  if (o >= R * Cc) return;
  int c = o % R, j = o / R;
  wt[o] = f2b(w[(size_t)c * Cc + j]);
}

// ---------------- exact f32 landmark q_l / k_l ----------------
__global__ void __launch_bounds__(256) k_lmk(
    const float* __restrict__ x, const float* __restrict__ w,
    const float* __restrict__ bias, float* __restrict__ qlf,
    float* __restrict__ klf, u16* __restrict__ qlb, u16* __restrict__ klb) {
  __shared__ __align__(16) float xr[512];
  const int t = threadIdx.x;
  const int b = blockIdx.x >> 6, i = blockIdx.x & 63;
  const int idx = (i * 8191) / 63;   // == np.linspace(0,8191,64).astype(int32)
  const float4* xg = (const float4*)(x + ((size_t)b*8192 + idx)*512);
  if (t < 128) ((float4*)xr)[t] = xg[t];
  __syncthreads();

  const int o0 = t << 2;
  float4 acc = *(const float4*)(bias + o0);
  const float* wp = w + o0;
  #pragma unroll 8
  for (int c = 0; c < 512; ++c) {
    const float xv = xr[c];
    const float4 wv = *(const float4*)(wp + (size_t)c*1536);
    acc.x = fmaf(xv, wv.x, acc.x); acc.y = fmaf(xv, wv.y, acc.y);
    acc.z = fmaf(xv, wv.z, acc.z); acc.w = fmaf(xv, wv.w, acc.w);
  }

  const int h = (o0 >> 6) & 7, d = o0 & 63;
  const size_t ofs = ((size_t)(b*8 + h)*64 + i)*64 + d;
  ushort4 pk;
  pk.x = f2b(acc.x); pk.y = f2b(acc.y); pk.z = f2b(acc.z); pk.w = f2b(acc.w);
  if (o0 < 512) { *(float4*)(qlf + ofs) = acc; *(ushort4*)(qlb + ofs) = pk; }
  else          { *(float4*)(klf + ofs) = acc; *(ushort4*)(klb + ofs) = pk; }
}

// ---------------- 128x128 tile bf16 MFMA GEMM (A[M][K] @ Bt[N][K]^T) ----------------
// MODE 0: qkv epilogue + 32 FUSED K2-INVERSION blocks (wgid<32): r10's proven
// configuration -- fused dispatch 148us, best total 273us. r11-r17 established
// that neither gemm occupancy (VGPR 88-132 all ~148-190) nor barrier removal
// (single-wave inv: 190) beats this; the 4-wave 2-barrier inv under contention
// IS the ~148 floor.
// MODE 1: f32 epilogue (out[M][Nout] = acc + bias), no fusion.
template <int MODE>
__global__ void __launch_bounds__(256) k_gemm(
    const u16* __restrict__ A, const u16* __restrict__ Bt,
    const float* __restrict__ bias, int K, int ntn,
    u16* __restrict__ qdst, u16* __restrict__ kdst, u16* __restrict__ vtdst,
    float* __restrict__ fout, int Nout,
    const float* __restrict__ qlf, const float* __restrict__ klf,
    float* __restrict__ invg) {
  constexpr int SMEM_BYTES = (MODE == 0) ? 34064 : 32768;  // union(gemm 32K, inv 33.8K)
  __shared__ __align__(16) char smem[SMEM_BYTES];
  const int t = threadIdx.x;
  // XCD swizzle: gridDim.x % 8 == 0 for all call sites -> bijective
  const int cpx = gridDim.x >> 3;
  const int wgid = (blockIdx.x & 7) * cpx + (blockIdx.x >> 3);

  if (MODE == 0 && wgid < 32) {
    // ======== fused K2 softmax + LDS Gauss-Jordan inverse (r7 core) ========
    float* Am = (float*)smem;                  // [64][132] augmented, stride 132
    int* pivcol = (int*)(smem + 33792);
    int* piv_sp = (int*)(smem + 33792 + 256);
    float4* A4 = (float4*)Am;
    const int bh = wgid;
    const int i4 = t >> 2, jc = t & 3;

    // stage k_l rows into the (currently dead) right half: Am[j][64+d]
    const float4* kg = (const float4*)(klf + (size_t)bh*4096);
    for (int g = t; g < 1024; g += 256) {
      int j = g >> 4, d4 = g & 15;
      ((float4*)(Am + j*132 + 64))[d4] = kg[g];
    }
    __syncthreads();

    // logits: Am[i][j] = (q_l[i] . k_l[j]) * 0.125 ; q from L2, k from LDS right half
    {
      float4 qreg[16];
      const float4* qg = (const float4*)(qlf + (size_t)bh*4096 + (size_t)i4*64);
      #pragma unroll
      for (int q4 = 0; q4 < 16; ++q4) qreg[q4] = qg[q4];
      #pragma unroll
      for (int jj = 0; jj < 16; ++jj) {
        int j = jc*16 + jj;
        const float4* kv4 = (const float4*)(Am + j*132 + 64);
        float acc = 0.f;
        #pragma unroll
        for (int q4 = 0; q4 < 16; ++q4) {
          float4 kv = kv4[q4];
          acc = fmaf(qreg[q4].x, kv.x, acc); acc = fmaf(qreg[q4].y, kv.y, acc);
          acc = fmaf(qreg[q4].z, kv.z, acc); acc = fmaf(qreg[q4].w, kv.w, acc);
        }
        Am[i4*132 + j] = acc * 0.125f;
      }
    }
    __syncthreads();   // all dots done before identity overwrites k_l

    // row softmax (4 lanes/row) + identity augment
    {
      float z[16]; float m = -1e30f;
      #pragma unroll
      for (int jj = 0; jj < 16; ++jj) { z[jj] = Am[i4*132 + jc*16 + jj]; m = fmaxf(m, z[jj]); }
      m = fmaxf(m, __shfl_xor(m, 1)); m = fmaxf(m, __shfl_xor(m, 2));
      float s = 0.f;
      #pragma unroll
      for (int jj = 0; jj < 16; ++jj) { z[jj] = __expf(z[jj] - m); s += z[jj]; }
      s += __shfl_xor(s, 1); s += __shfl_xor(s, 2);
      float rinv = 1.f / s;
      #pragma unroll
      for (int jj = 0; jj < 16; ++jj) {
        int j = jc*16 + jj;
        Am[i4*132 + j] = z[jj] * rinv;
        Am[i4*132 + 64 + j] = (j == i4) ? 1.f : 0.f;
      }
    }
    __syncthreads();

    // Gauss-Jordan: virtual pivot, no normalize, 2 barriers/col
    const int r = i4, q = jc;
    int used = 0;
    for (int c = 0; c < 64; ++c) {
      if (t < 64) {
        float val = used ? -1.f : fabsf(Am[t*132 + c]);
        int idx = t;
        #pragma unroll
        for (int mk = 1; mk < 64; mk <<= 1) {
          float ov = __shfl_xor(val, mk);
          int oi = __shfl_xor(idx, mk);
          int take = (ov > val) || (ov == val && oi < idx);
          val = take ? ov : val;
          idx = take ? oi : idx;
        }
        if (t == idx) { used = 1; pivcol[t] = c; }
        if (t == 0) *piv_sp = idx;
      }
      __syncthreads();
      const int p = *piv_sp;
      if (r != p) {
        const float coef = -Am[r*132 + c] / Am[p*132 + c];
        const float4* Ap = A4 + p*33 + q*8;
        float4* Ar = A4 + r*33 + q*8;
        #pragma unroll
        for (int i = 0; i < 8; ++i) {
          float4 a = Ar[i], pv = Ap[i];
          a.x = fmaf(coef, pv.x, a.x); a.y = fmaf(coef, pv.y, a.y);
          a.z = fmaf(coef, pv.z, a.z); a.w = fmaf(coef, pv.w, a.w);
          Ar[i] = a;
        }
      }
      __syncthreads();
    }

    // extraction: inv[pivcol[r]][j] = Am[r][64+j] / Am[r][pivcol[r]]
    {
      const int cr = pivcol[r];
      const float rd = 1.f / Am[r*132 + cr];
      float4* og = (float4*)(invg + (size_t)bh*4096 + (size_t)cr*64) + q*4;
      #pragma unroll
      for (int i = 0; i < 4; ++i) {
        float4 v = A4[r*33 + 16 + q*4 + i];
        v.x *= rd; v.y *= rd; v.z *= rd; v.w *= rd;
        og[i] = v;
      }
    }
    return;
  }

  // ======== GEMM path ========
  u16* As = (u16*)smem;
  u16* Bs = (u16*)(smem + 16384);
  const int wg2 = wgid - (MODE == 0 ? 32 : 0);
  const int tn = wg2 % ntn, tm = wg2 / ntn;
  const int m0 = tm << 7, n0 = tn << 7;
  const int w = t >> 6, l = t & 63;
  const int wr = (w >> 1) << 6, wc = (w & 1) << 6;
  const int lhi = l >> 4, llo = l & 15;

  f32x4 acc[4][4];
  #pragma unroll
  for (int i = 0; i < 4; ++i)
    #pragma unroll
    for (int j = 0; j < 4; ++j) acc[i][j] = f32x4{0.f,0.f,0.f,0.f};

  // staged rows advance by 32 (≡0 mod 8), so row&7 == (t>>3)&7 for all i
  const int csw = (((t & 7) ^ ((t >> 3) & 7)) << 3);
  const u16* ga = A  + (size_t)(m0 + (t >> 3)) * K + csw;
  const u16* gb = Bt + (size_t)(n0 + (t >> 3)) * K + csw;
  u16* lA = As + (w << 9);
  u16* lB = Bs + (w << 9);

  for (int kt = 0; kt < K; kt += 64) {
    __syncthreads();
    #pragma unroll
    for (int i = 0; i < 4; ++i) {
      gload16(ga + (size_t)(i*32)*K + kt, lA + i*2048);
      gload16(gb + (size_t)(i*32)*K + kt, lB + i*2048);
    }
    VMCNT0;
    __syncthreads();
    #pragma unroll
    for (int kko = 0; kko < 64; kko += 32) {
      const int kc = kko >> 3;     // chunk base: 0 or 4
      bf16x8 av[4], bv[4];
      #pragma unroll
      for (int mi = 0; mi < 4; ++mi)
        av[mi] = *(const bf16x8*)(As + swz64(wr + mi*16 + llo, kc + lhi));
      #pragma unroll
      for (int ni = 0; ni < 4; ++ni)
        bv[ni] = *(const bf16x8*)(Bs + swz64(wc + ni*16 + llo, kc + lhi));
      #pragma unroll
      for (int mi = 0; mi < 4; ++mi)
        #pragma unroll
        for (int ni = 0; ni < 4; ++ni)
          acc[mi][ni] = mfma16(av[mi], bv[ni], acc[mi][ni]);
    }
  }

  #pragma unroll
  for (int ni = 0; ni < 4; ++ni) {
    const int gcol = n0 + wc + ni*16 + llo;
    const float bvv = bias[gcol];
    if (MODE == 0) {
      const int tt = gcol >> 9, h = (gcol >> 6) & 7, d = gcol & 63;
      #pragma unroll
      for (int mi = 0; mi < 4; ++mi) {
        const int grow = m0 + wr + mi*16 + (lhi << 2);
        const int b = grow >> 13, n = grow & 8191;
        const size_t bh = (size_t)(b*8 + h);
        if (tt == 2) {
          ushort4 pk;
          pk.x = f2b(acc[mi][ni][0] + bvv); pk.y = f2b(acc[mi][ni][1] + bvv);
          pk.z = f2b(acc[mi][ni][2] + bvv); pk.w = f2b(acc[mi][ni][3] + bvv);
          *(ushort4*)(vtdst + (bh*64 + d)*8192 + n) = pk;
        } else {
          u16* dst = (tt == 0 ? qdst : kdst) + (bh*8192 + n)*64 + d;
          #pragma unroll
          for (int r = 0; r < 4; ++r) dst[(size_t)r*64] = f2b(acc[mi][ni][r] + bvv);
        }
      }
    } else {
      #pragma unroll
      for (int mi = 0; mi < 4; ++mi) {
        const int grow = m0 + wr + mi*16 + (lhi << 2);
        #pragma unroll
        for (int r = 0; r < 4; ++r)
          fout[(size_t)(grow + r)*Nout + gcol] = acc[mi][ni][r] + bvv;
      }
    }
  }
}

// ---------------- kernel_3 partials: num = sum_n e^{q_l.k/8} v, den = sum_n e^{...} ----------------
__global__ void __launch_bounds__(256) k_flash3(
    const u16* __restrict__ qlb, const u16* __restrict__ kmat,
    const u16* __restrict__ vt, float* __restrict__ num_part,
    float* __restrict__ den_part) {
  __shared__ __align__(16) u16 QL[64*64];
  __shared__ __align__(16) u16 KT[4][64*64];
  __shared__ __align__(16) u16 VT[4][64*64];
  __shared__ __align__(16) u16 PL[4][64*64];
  const int t = threadIdx.x, w = t >> 6, l = t & 63;
  const int bh = blockIdx.x >> 3, split = blockIdx.x & 7;
  const int lhi = l >> 4, llo = l & 15;
  const int csw = ((l & 7) ^ (l >> 3)) << 3;       // source chunk pre-swizzle

  #pragma unroll
  for (int i = 0; i < 2; ++i)
    gload16(qlb + (size_t)bh*4096 + (size_t)((i*256 + (t & ~7)) << 3)
                + (((t & 7) ^ ((t >> 3) & 7)) << 3),
            QL + i*2048 + (w << 9));
  VMCNT0;
  __syncthreads();

  f32x4 oacc[4][4];
  float dacc[4][4];
  #pragma unroll
  for (int a = 0; a < 4; ++a)
    #pragma unroll
    for (int bq = 0; bq < 4; ++bq) { oacc[a][bq] = f32x4{0.f,0.f,0.f,0.f}; dacc[a][bq] = 0.f; }

  const int nb = split << 10;
  u16* lk = KT[w]; u16* lv = VT[w]; u16* lp = PL[w];
  for (int j = 0; j < 4; ++j) {
    const int n0 = nb + ((w + 4*j) << 6);
    const u16* gk = kmat + ((size_t)bh*8192 + n0 + (l >> 3))*64 + csw;
    const u16* gv = vt   + ((size_t)bh*64 + (l >> 3))*8192 + n0 + csw;
    asm volatile("" ::: "memory");
    LGKM0;   // drain prior iter's ds_reads before DMA overwrites lk/lv
    #pragma unroll
    for (int i = 0; i < 8; ++i) {
      gload16(gk + (size_t)(i*8)*64, lk + i*512);
      gload16(gv + (size_t)(i*8)*8192, lv + i*512);
    }
    VMCNT0;

    f32x4 s[4][4];
    #pragma unroll
    for (int qi = 0; qi < 4; ++qi)
      #pragma unroll
      for (int nj = 0; nj < 4; ++nj) s[qi][nj] = f32x4{0.f,0.f,0.f,0.f};
    #pragma unroll
    for (int kko = 0; kko < 64; kko += 32) {
      const int kc = kko >> 3;
      bf16x8 av[4], bv[4];
      #pragma unroll
      for (int qi = 0; qi < 4; ++qi)
        av[qi] = *(const bf16x8*)(QL + swz64(qi*16 + llo, kc + lhi));
      #pragma unroll
      for (int nj = 0; nj < 4; ++nj)
        bv[nj] = *(const bf16x8*)(lk + swz64(nj*16 + llo, kc + lhi));
      #pragma unroll
      for (int qi = 0; qi < 4; ++qi)
        #pragma unroll
        for (int nj = 0; nj < 4; ++nj)
          s[qi][nj] = mfma16(av[qi], bv[nj], s[qi][nj]);
    }
    #pragma unroll
    for (int qi = 0; qi < 4; ++qi) {
      float rs[4] = {0.f, 0.f, 0.f, 0.f};
      #pragma unroll
      for (int nj = 0; nj < 4; ++nj)
        #pragma unroll
        for (int r = 0; r < 4; ++r) {
          float p = __expf(s[qi][nj][r] * 0.125f);  // logits bounded, no max needed
          rs[r] += p;
          const int prow = qi*16 + lhi*4 + r, pcol = nj*16 + llo;
          lp[swz64(prow, pcol >> 3) + (pcol & 7)] = f2b(p);
        }
      #pragma unroll
      for (int r = 0; r < 4; ++r) {
        float v = rs[r];
        v += __shfl_xor(v, 1); v += __shfl_xor(v, 2);
        v += __shfl_xor(v, 4); v += __shfl_xor(v, 8);
        dacc[qi][r] += v;
      }
    }
    LGKM0;
    #pragma unroll
    for (int kko = 0; kko < 64; kko += 32) {
      const int kc = kko >> 3;
      bf16x8 pa[4], vb[4];
      #pragma unroll
      for (int qi = 0; qi < 4; ++qi)
        pa[qi] = *(const bf16x8*)(lp + swz64(qi*16 + llo, kc + lhi));
      #pragma unroll
      for (int dj = 0; dj < 4; ++dj)
        vb[dj] = *(const bf16x8*)(lv + swz64(dj*16 + llo, kc + lhi));
      #pragma unroll
      for (int qi = 0; qi < 4; ++qi)
        #pragma unroll
        for (int dj = 0; dj < 4; ++dj)
          oacc[qi][dj] = mfma16(pa[qi], vb[dj], oacc[qi][dj]);
    }
  }
  const int sw = (split << 2) + w;
  float* np = num_part + ((size_t)bh*32 + sw)*4096;
  #pragma unroll
  for (int qi = 0; qi < 4; ++qi)
    #pragma unroll
    for (int dj = 0; dj < 4; ++dj)
      #pragma unroll
      for (int r = 0; r < 4; ++r)
        np[(qi*16 + lhi*4 + r)*64 + dj*16 + llo] = oacc[qi][dj][r];
  if (llo == 0) {
    float* dp = den_part + ((size_t)bh*32 + sw)*64;
    #pragma unroll
    for (int qi = 0; qi < 4; ++qi)
      #pragma unroll
      for (int r = 0; r < 4; ++r)
        dp[qi*16 + lhi*4 + r] = dacc[qi][r];
  }
}

// ---------------- T1 = (sum_s num_part) / den : wide reduce ----------------
__global__ void __launch_bounds__(256) k_t1(
    const float* __restrict__ num_part, const float* __restrict__ den_part,
    float* __restrict__ t1g) {
  const int t = threadIdx.x;
  const int bh = blockIdx.x >> 2, ch = blockIdx.x & 3;
  const int f = ch*256 + t;                 // float4 index in [0,1024)
  const int m = f >> 4;                     // landmark row
  const float4* ng = (const float4*)num_part + (size_t)bh*32*1024;
  float4 acc = {0.f, 0.f, 0.f, 0.f};
  float ds = 0.f;
  for (int s = 0; s < 32; ++s) {
    float4 v = ng[(size_t)s*1024 + f];
    acc.x += v.x; acc.y += v.y; acc.z += v.z; acc.w += v.w;
    ds += den_part[((size_t)bh*32 + s)*64 + m];
  }
  float r = 1.f / ds;
  acc.x *= r; acc.y *= r; acc.z *= r; acc.w *= r;
  ((float4*)t1g)[(size_t)bh*1024 + f] = acc;
}

// ---------------- t2^T = (Inv @ T1)^T ----------------
__global__ void __launch_bounds__(256) k_t2(
    const float* __restrict__ invg, const float* __restrict__ t1g,
    float* __restrict__ t2t) {
  __shared__ __align__(16) float IV[64*68];
  __shared__ __align__(16) float T1[64*68];
  const int t = threadIdx.x;
  const int bh = blockIdx.x;
  const int i4 = t >> 2, jc = t & 3;
  float4* IV4 = (float4*)IV;
  float4* T14 = (float4*)T1;
  const float4* ig = (const float4*)(invg + (size_t)bh*4096);
  const float4* tg = (const float4*)(t1g + (size_t)bh*4096);
  #pragma unroll
  for (int k = 0; k < 4; ++k) {
    int g = k*256 + t, row = g >> 4, c4 = g & 15;
    IV4[row*17 + c4] = ig[g];
    T14[row*17 + c4] = tg[g];
  }
  __syncthreads();
  float acc[16];
  #pragma unroll
  for (int d = 0; d < 16; ++d) acc[d] = 0.f;
  for (int m = 0; m < 64; ++m) {
    float wv = IV[i4*68 + m];
    #pragma unroll
    for (int d4 = 0; d4 < 4; ++d4) {
      float4 tv = T14[m*17 + jc*4 + d4];
      acc[d4*4+0] = fmaf(wv, tv.x, acc[d4*4+0]);
      acc[d4*4+1] = fmaf(wv, tv.y, acc[d4*4+1]);
      acc[d4*4+2] = fmaf(wv, tv.z, acc[d4*4+2]);
      acc[d4*4+3] = fmaf(wv, tv.w, acc[d4*4+3]);
    }
  }
  #pragma unroll
  for (int dd = 0; dd < 16; ++dd) {
    int d = jc*16 + dd;
    t2t[((size_t)bh*64 + d)*64 + i4] = acc[dd];
  }
}

// ---------------- fused kernel_1 softmax + @t2 -> out_att bf16 [B][N][C] ----------------
__global__ void __launch_bounds__(256) k_flash1(
    const u16* __restrict__ q, const u16* __restrict__ klb,
    const float* __restrict__ t2t, u16* __restrict__ oatt) {
  __shared__ __align__(16) u16 KL[64*64];
  __shared__ __align__(16) u16 T2[64*64];
  __shared__ __align__(16) u16 QT[4][64*64];
  __shared__ __align__(16) u16 PL[4][64*64];
  const int t = threadIdx.x, w = t >> 6, l = t & 63;
  const int bh = blockIdx.x >> 5, blk = blockIdx.x & 31;
  const int lhi = l >> 4, llo = l & 15;
  const int b = bh >> 3, h = bh & 7;
  const int csw = ((l & 7) ^ (l >> 3)) << 3;

  #pragma unroll
  for (int i = 0; i < 2; ++i)
    gload16(klb + (size_t)bh*4096 + (size_t)((i*256 + (t & ~7)) << 3)
                + (((t & 7) ^ ((t >> 3) & 7)) << 3),
            KL + i*2048 + (w << 9));
  for (int i = t; i < 4096; i += 256)
    T2[swz64(i >> 6, (i & 63) >> 3) + (i & 7)] = f2b(t2t[(size_t)bh*4096 + i]);
  VMCNT0;
  __syncthreads();

  const int n0 = (blk << 8) + (w << 6);
  const u16* gq = q + ((size_t)bh*8192 + n0 + (l >> 3))*64 + csw;
  u16* lq = QT[w]; u16* lp = PL[w];
  #pragma unroll
  for (int i = 0; i < 8; ++i) gload16(gq + (size_t)(i*8)*64, lq + i*512);
  VMCNT0;

  f32x4 s[4][4];
  #pragma unroll
  for (int qi = 0; qi < 4; ++qi)
    #pragma unroll
    for (int nj = 0; nj < 4; ++nj) s[qi][nj] = f32x4{0.f,0.f,0.f,0.f};
  #pragma unroll
  for (int kko = 0; kko < 64; kko += 32) {
    const int kc = kko >> 3;
    bf16x8 av[4], bv[4];
    #pragma unroll
    for (int qi = 0; qi < 4; ++qi)
      av[qi] = *(const bf16x8*)(lq + swz64(qi*16 + llo, kc + lhi));
    #pragma unroll
    for (int nj = 0; nj < 4; ++nj)
      bv[nj] = *(const bf16x8*)(KL + swz64(nj*16 + llo, kc + lhi));
    #pragma unroll
    for (int qi = 0; qi < 4; ++qi)
      #pragma unroll
      for (int nj = 0; nj < 4; ++nj)
        s[qi][nj] = mfma16(av[qi], bv[nj], s[qi][nj]);
  }
  float rcp_[4][4];
  #pragma unroll
  for (int qi = 0; qi < 4; ++qi) {
    float mx[4] = {-1e30f, -1e30f, -1e30f, -1e30f};
    #pragma unroll
    for (int nj = 0; nj < 4; ++nj)
      #pragma unroll
      for (int r = 0; r < 4; ++r) {
        float z = s[qi][nj][r] * 0.125f;
        s[qi][nj][r] = z;
        mx[r] = fmaxf(mx[r], z);
      }
    #pragma unroll
    for (int r = 0; r < 4; ++r) {
      float m = mx[r];
      m = fmaxf(m, __shfl_xor(m, 1)); m = fmaxf(m, __shfl_xor(m, 2));
      m = fmaxf(m, __shfl_xor(m, 4)); m = fmaxf(m, __shfl_xor(m, 8));
      mx[r] = m;
    }
    float rs[4] = {0.f, 0.f, 0.f, 0.f};
    #pragma unroll
    for (int nj = 0; nj < 4; ++nj)
      #pragma unroll
      for (int r = 0; r < 4; ++r) {
        float p = __expf(s[qi][nj][r] - mx[r]);
        rs[r] += p;
        const int prow = qi*16 + lhi*4 + r, pcol = nj*16 + llo;
        lp[swz64(prow, pcol >> 3) + (pcol & 7)] = f2b(p);
      }
    #pragma unroll
    for (int r = 0; r < 4; ++r) {
      float v = rs[r];
      v += __shfl_xor(v, 1); v += __shfl_xor(v, 2);
      v += __shfl_xor(v, 4); v += __shfl_xor(v, 8);
      rcp_[qi][r] = 1.0f / v;
    }
  }
  LGKM0;
  f32x4 o[4][4];
  #pragma unroll
  for (int qi = 0; qi < 4; ++qi)
    #pragma unroll
    for (int dj = 0; dj < 4; ++dj) o[qi][dj] = f32x4{0.f,0.f,0.f,0.f};
  #pragma unroll
  for (int kko = 0; kko < 64; kko += 32) {
    const int kc = kko >> 3;
    bf16x8 pa[4], tb[4];
    #pragma unroll
    for (int qi = 0; qi < 4; ++qi)
      pa[qi] = *(const bf16x8*)(lp + swz64(qi*16 + llo, kc + lhi));
    #pragma unroll
    for (int dj = 0; dj < 4; ++dj)
      tb[dj] = *(const bf16x8*)(T2 + swz64(dj*16 + llo, kc + lhi));
    #pragma unroll
    for (int qi = 0; qi < 4; ++qi)
      #pragma unroll
      for (int dj = 0; dj < 4; ++dj)
        o[qi][dj] = mfma16(pa[qi], tb[dj], o[qi][dj]);
  }
  #pragma unroll
  for (int qi = 0; qi < 4; ++qi)
    #pragma unroll
    for (int dj = 0; dj < 4; ++dj)
      #pragma unroll
      for (int r = 0; r < 4; ++r) {
        int n = n0 + qi*16 + lhi*4 + r;
        oatt[((size_t)b*8192 + n)*512 + h*64 + dj*16 + llo] = f2b(o[qi][dj][r] * rcp_[qi][r]);
      }
}

// ---------------- launch ----------------
extern "C" void kernel_launch(void* const* d_in, const int* in_sizes, int n_in,
                              void* d_out, int out_size, void* d_ws, size_t ws_size,
                              hipStream_t stream) {
  const float* x      = (const float*)d_in[0];
  const float* qkv_w  = (const float*)d_in[1];
  const float* qkv_b  = (const float*)d_in[2];
  const float* proj_w = (const float*)d_in[3];
  const float* proj_b = (const float*)d_in[4];
  float* out = (float*)d_out;

  char* ws = (char*)d_ws;
  size_t off = 0;
  auto alloc = [&](size_t bytes) -> char* {
    char* p = ws + off;
    off += (bytes + 255) & ~(size_t)255;
    return p;
  };
  u16*   x_bf  = (u16*)  alloc(33554432);   // x bf16; reused as out_att after GEMM1
  u16*   vt    = (u16*)  alloc(33554432);   // v^T bf16 [BH][64][8192]
  u16*   wqkvt = (u16*)  alloc(1572864);    // qkv_w^T bf16 [1536][512]
  u16*   wprjt = (u16*)  alloc(524288);     // proj_w^T bf16 [512][512]
  float* qlf   = (float*)alloc(524288);     // q_l f32 [BH][64][64]
  float* klf   = (float*)alloc(524288);
  u16*   qlb   = (u16*)  alloc(262144);     // bf16 copies
  u16*   klb   = (u16*)  alloc(262144);
  float* nump  = (float*)alloc(16777216);   // t1 numerator partials [BH][32][64][64]
  float* denp  = (float*)alloc(262144);     // denominator partials  [BH][32][64]
  float* t2t   = (float*)alloc(524288);     // t2^T f32 [BH][64][64]
  float* t1g   = (float*)alloc(524288);     // T1 f32 [BH][64][64]
  float* invg  = (float*)alloc(524288);     // K2^-1 f32 [BH][64][64]
  if (off > ws_size) return;                // insufficient scratch -> fail loudly

  u16* qm   = (u16*)d_out;                  // q bf16 [BH][8192][64] (dead before proj writes)
  u16* kmat = qm + 16777216;                // k bf16
  u16* oatt = x_bf;                         // out_att bf16 [B][N][C]

  k_cast_x<<<8192, 256, 0, stream>>>((const float4*)x, (uint4*)x_bf, 2097152);
  k_tcast<<<3072, 256, 0, stream>>>(qkv_w, wqkvt, 512, 1536);
  k_tcast<<<1024, 256, 0, stream>>>(proj_w, wprjt, 512, 512);
  k_lmk<<<256, 256, 0, stream>>>(x, qkv_w, qkv_b, qlf, klf, qlb, klb);
  // fused: 3072 gemm blocks + 32 inversion blocks (wgid<32, dispatched first)
  k_gemm<0><<<3104, 256, 0, stream>>>(x_bf, wqkvt, qkv_b, 512, 12, qm, kmat, vt,
                                      nullptr, 0, qlf, klf, invg);
  k_flash3<<<256, 256, 0, stream>>>(qlb, kmat, vt, nump, denp);
  k_t1<<<128, 256, 0, stream>>>(nump, denp, t1g);
  k_t2<<<32, 256, 0, stream>>>(invg, t1g, t2t);
  k_flash1<<<1024, 256, 0, stream>>>(qm, klb, t2t, oatt);
  k_gemm<1><<<1024, 256, 0, stream>>>(oatt, wprjt, proj_b, 512, 4, nullptr, nullptr,
                                      nullptr, out, 512, nullptr, nullptr, nullptr);
}